// Round 2
// baseline (164.592 us; speedup 1.0000x reference)
//
#include <hip/hip_runtime.h>

#define BB 16
#define CC 768
#define DD 128
#define NN 4096

typedef float f32x4 __attribute__((ext_vector_type(4)));
typedef __bf16 bf16x8 __attribute__((ext_vector_type(8)));
typedef __bf16 bf16x4 __attribute__((ext_vector_type(4)));

__device__ __forceinline__ float wave_reduce_max(float x) {
#pragma unroll
  for (int off = 32; off > 0; off >>= 1) x = fmaxf(x, __shfl_xor(x, off, 64));
  return x;
}
__device__ __forceinline__ float wave_reduce_sum(float x) {
#pragma unroll
  for (int off = 32; off > 0; off >>= 1) x += __shfl_xor(x, off, 64);
  return x;
}

// K1: per (b,d) row: softmax stats over n (max, 1/sum). Also zero hmat accumulator.
// NOTE: softmax(dt + A[d]) over n == softmax(dt) over n (A constant along axis) -> A unused.
__global__ __launch_bounds__(256) void k_stats(const float* __restrict__ BCdt,
                                               float* __restrict__ stats,
                                               float* __restrict__ hmat) {
  int blk = blockIdx.x;  // b*128 + d
  int b = blk >> 7, d = blk & 127;
  const float4* row = (const float4*)(BCdt + ((size_t)b * (2 * DD) + (DD + d)) * NN);
  int t = threadIdx.x;
  float4 v[4];
  float mx = -3.0e38f;
#pragma unroll
  for (int i = 0; i < 4; ++i) {
    v[i] = row[t + 256 * i];
    mx = fmaxf(mx, fmaxf(fmaxf(v[i].x, v[i].y), fmaxf(v[i].z, v[i].w)));
  }
  __shared__ float red[8];
  float wm = wave_reduce_max(mx);
  int wid = t >> 6;
  if ((t & 63) == 0) red[wid] = wm;
  __syncthreads();
  mx = fmaxf(fmaxf(red[0], red[1]), fmaxf(red[2], red[3]));
  float s = 0.f;
#pragma unroll
  for (int i = 0; i < 4; ++i)
    s += __expf(v[i].x - mx) + __expf(v[i].y - mx) + __expf(v[i].z - mx) + __expf(v[i].w - mx);
  float ws = wave_reduce_sum(s);
  if ((t & 63) == 0) red[4 + wid] = ws;
  __syncthreads();
  if (t == 0) {
    float tot = red[4] + red[5] + red[6] + red[7];
    stats[2 * blk] = mx;
    stats[2 * blk + 1] = 1.0f / tot;
  }
  // zero hmat: 2048 blocks * 768 floats == 16*768*128
  float* hz = hmat + (size_t)blk * 768;
#pragma unroll
  for (int i = 0; i < 3; ++i) hz[t + 256 * i] = 0.f;
}

// K1b: AB = softmax(dt)*BC -> bf16 [b][d][n]; BCt = BC^T -> bf16 [b][n][d].
__global__ __launch_bounds__(256) void k_prep(const float* __restrict__ BCdt,
                                              const float* __restrict__ stats,
                                              __bf16* __restrict__ AB,
                                              __bf16* __restrict__ BCt) {
  int blk = blockIdx.x;  // b*128 + dtile*64 + ntile
  int ntile = blk & 63;
  int dtile = (blk >> 6) & 1;
  int b = blk >> 7;
  int d0 = dtile * 64, n0 = ntile * 64;
  __shared__ __bf16 Ls[64][76];  // [d_local][n_local]
  int t = threadIdx.x;
  int r = t >> 4;   // 0..15
  int cg = t & 15;  // col group
  const float* base = BCdt + (size_t)b * (2 * DD) * NN;
#pragma unroll
  for (int p = 0; p < 4; ++p) {
    int dl = r + p * 16;
    int d = d0 + dl;
    float4 bc = *(const float4*)(base + (size_t)d * NN + n0 + cg * 4);
    float4 dt = *(const float4*)(base + (size_t)(DD + d) * NN + n0 + cg * 4);
    float mx = stats[2 * (b * DD + d)];
    float inv = stats[2 * (b * DD + d) + 1];
    bf16x4 abv;
    abv[0] = (__bf16)(__expf(dt.x - mx) * inv * bc.x);
    abv[1] = (__bf16)(__expf(dt.y - mx) * inv * bc.y);
    abv[2] = (__bf16)(__expf(dt.z - mx) * inv * bc.z);
    abv[3] = (__bf16)(__expf(dt.w - mx) * inv * bc.w);
    *(bf16x4*)(AB + ((size_t)(b * DD + d)) * NN + n0 + cg * 4) = abv;
    bf16x4 bcv;
    bcv[0] = (__bf16)bc.x; bcv[1] = (__bf16)bc.y; bcv[2] = (__bf16)bc.z; bcv[3] = (__bf16)bc.w;
    *(bf16x4*)(&Ls[dl][cg * 4]) = bcv;
  }
  __syncthreads();
#pragma unroll
  for (int p = 0; p < 4; ++p) {
    int j = r + p * 16;  // local n
    bf16x4 v;
#pragma unroll
    for (int k = 0; k < 4; ++k) v[k] = Ls[cg * 4 + k][j];
    *(bf16x4*)(BCt + ((size_t)b * NN + n0 + j) * DD + d0 + cg * 4) = v;
  }
}

// K2: hmat[b][c][d] += sum_n x[b][c][n]*AB[b][d][n]; 128x128 tile, split-K x8, atomic fp32.
__global__ __launch_bounds__(256) void k_hmat(const float* __restrict__ x,
                                              const __bf16* __restrict__ AB,
                                              float* __restrict__ hmat) {
  int blk = blockIdx.x;  // ((b*6 + mt)<<3) | q
  int q = blk & 7;
  int rest = blk >> 3;
  int mt = rest % 6;
  int b = rest / 6;
  int c0 = mt * 128;
  int kbase = q * 512;
  __shared__ __bf16 Xs[128][72];   // [c][k], 144B rows
  __shared__ __bf16 ABs[128][72];  // [d][k]
  int t = threadIdx.x;
  int lane = t & 63, w = t >> 6;
  int wr = w >> 1, wc = w & 1;
  int fr = lane & 15, fg = lane >> 4;
  f32x4 acc[4][4] = {};
  const float* xb = x + ((size_t)b * CC + c0) * NN + kbase;
  const __bf16* abb = AB + (size_t)b * DD * NN + kbase;
  int rr = t >> 4, cg = t & 15;
  int rr2 = t >> 3, cg2 = t & 7;
  for (int s = 0; s < 8; ++s) {
    int koff = s * 64;
#pragma unroll
    for (int p = 0; p < 8; ++p) {  // X: 128 rows x 64 fp32 -> bf16
      int row = rr + p * 16;
      float4 f = *(const float4*)(xb + (size_t)row * NN + koff + cg * 4);
      bf16x4 v;
      v[0] = (__bf16)f.x; v[1] = (__bf16)f.y; v[2] = (__bf16)f.z; v[3] = (__bf16)f.w;
      *(bf16x4*)(&Xs[row][cg * 4]) = v;
    }
#pragma unroll
    for (int p = 0; p < 4; ++p) {  // AB: 128 rows x 64 bf16, 16B copies
      int row = rr2 + p * 32;
      uint4 u = *(const uint4*)(abb + (size_t)row * NN + koff + cg2 * 8);
      *(uint4*)(&ABs[row][cg2 * 8]) = u;
    }
    __syncthreads();
#pragma unroll
    for (int kk = 0; kk < 2; ++kk) {
      bf16x8 a[4], bfr[4];
#pragma unroll
      for (int i = 0; i < 4; ++i)
        a[i] = *(const bf16x8*)(&Xs[wr * 64 + i * 16 + fr][kk * 32 + fg * 8]);
#pragma unroll
      for (int i = 0; i < 4; ++i)
        bfr[i] = *(const bf16x8*)(&ABs[wc * 64 + i * 16 + fr][kk * 32 + fg * 8]);
#pragma unroll
      for (int mi = 0; mi < 4; ++mi)
#pragma unroll
        for (int ni = 0; ni < 4; ++ni)
          acc[mi][ni] = __builtin_amdgcn_mfma_f32_16x16x32_bf16(a[mi], bfr[ni], acc[mi][ni], 0, 0, 0);
    }
    __syncthreads();
  }
  float* hb = hmat + (size_t)b * CC * DD;
#pragma unroll
  for (int mi = 0; mi < 4; ++mi)
#pragma unroll
    for (int ni = 0; ni < 4; ++ni)
#pragma unroll
      for (int ri = 0; ri < 4; ++ri) {
        int rowc = c0 + wr * 64 + mi * 16 + fg * 4 + ri;
        int cold = wc * 64 + ni * 16 + fr;
        atomicAdd(hb + (size_t)rowc * DD + cold, acc[mi][ni][ri]);
      }
}

// K3: y[b][c][n] = sum_d hmat[b][c][d]*BC[b][d][n]; 128c x 128n tile, K=128 single stage.
// Output is FLOAT32 (reference is pure fp32 JAX). Epilogue restages tile in LDS
// (reusing the bf16 staging buffer) for fully-coalesced float4 stores.
__global__ __launch_bounds__(256) void k_y(const float* __restrict__ hmat,
                                           const __bf16* __restrict__ BCt,
                                           float* __restrict__ y) {
  int blk = blockIdx.x;  // ((b*6+mt)<<5) | nt
  int nt = blk & 31;
  int rest = blk >> 5;
  int mt = rest % 6;
  int b = rest / 6;
  int c0 = mt * 128, n0 = nt * 128;
  // union: Hs[128][136] bf16 (34816B) + Bs[128][136] bf16 (34816B)  vs  St[128][132] f32 (67584B)
  __shared__ __align__(16) char smem[69632];
  __bf16(*Hs)[136] = (__bf16(*)[136])smem;
  __bf16(*Bs)[136] = (__bf16(*)[136])(smem + 34816);
  float(*St)[132] = (float(*)[132])smem;
  int t = threadIdx.x;
  {
    int rr = t >> 5, cg = t & 31;
    const float* hb = hmat + ((size_t)b * CC + c0) * DD;
#pragma unroll
    for (int p = 0; p < 16; ++p) {
      int row = rr + p * 8;
      float4 f = *(const float4*)(hb + (size_t)row * DD + cg * 4);
      bf16x4 v;
      v[0] = (__bf16)f.x; v[1] = (__bf16)f.y; v[2] = (__bf16)f.z; v[3] = (__bf16)f.w;
      *(bf16x4*)(&Hs[row][cg * 4]) = v;
    }
    int rr2 = t >> 4, cg2 = t & 15;
    const __bf16* bb = BCt + ((size_t)b * NN + n0) * DD;
#pragma unroll
    for (int p = 0; p < 8; ++p) {
      int row = rr2 + p * 16;
      uint4 u = *(const uint4*)(bb + (size_t)row * DD + cg2 * 8);
      *(uint4*)(&Bs[row][cg2 * 8]) = u;
    }
  }
  __syncthreads();
  int lane = t & 63, w = t >> 6;
  int wr = w >> 1, wc = w & 1;
  int fr = lane & 15, fg = lane >> 4;
  f32x4 acc[4][4] = {};
#pragma unroll
  for (int kk = 0; kk < 4; ++kk) {
    bf16x8 a[4], bfr[4];
#pragma unroll
    for (int i = 0; i < 4; ++i)
      a[i] = *(const bf16x8*)(&Hs[wr * 64 + i * 16 + fr][kk * 32 + fg * 8]);
#pragma unroll
    for (int i = 0; i < 4; ++i)
      bfr[i] = *(const bf16x8*)(&Bs[wc * 64 + i * 16 + fr][kk * 32 + fg * 8]);
#pragma unroll
    for (int mi = 0; mi < 4; ++mi)
#pragma unroll
      for (int ni = 0; ni < 4; ++ni)
        acc[mi][ni] = __builtin_amdgcn_mfma_f32_16x16x32_bf16(a[mi], bfr[ni], acc[mi][ni], 0, 0, 0);
  }
  __syncthreads();  // all Hs/Bs reads done; reuse smem as f32 stage
#pragma unroll
  for (int mi = 0; mi < 4; ++mi)
#pragma unroll
    for (int ni = 0; ni < 4; ++ni)
#pragma unroll
      for (int ri = 0; ri < 4; ++ri) {
        int rowc = wr * 64 + mi * 16 + fg * 4 + ri;
        int coln = wc * 64 + ni * 16 + fr;
        St[rowc][coln] = acc[mi][ni][ri];
      }
  __syncthreads();
  float* yb = y + ((size_t)b * CC + c0) * NN + n0;
  int rr3 = t >> 5, cg3 = t & 31;
#pragma unroll
  for (int p = 0; p < 16; ++p) {
    int row = rr3 + p * 8;
    float4 v = *(const float4*)(&St[row][cg3 * 4]);
    *(float4*)(yb + (size_t)row * NN + cg3 * 4) = v;
  }
}

extern "C" void kernel_launch(void* const* d_in, const int* in_sizes, int n_in,
                              void* d_out, int out_size, void* d_ws, size_t ws_size,
                              hipStream_t stream) {
  (void)in_sizes; (void)n_in; (void)out_size; (void)ws_size;
  const float* BCdt = (const float*)d_in[0];
  const float* x = (const float*)d_in[1];
  // d_in[2] (A) unused: softmax shift-invariance.
  char* ws = (char*)d_ws;
  size_t offAB = 0;
  size_t offBCt = offAB + (size_t)BB * DD * NN * 2;   // 16.78 MB
  size_t offH = offBCt + (size_t)BB * NN * DD * 2;    // +16.78 MB
  size_t offS = offH + (size_t)BB * CC * DD * 4;      // +6.29 MB
  __bf16* AB = (__bf16*)(ws + offAB);
  __bf16* BCt = (__bf16*)(ws + offBCt);
  float* hmat = (float*)(ws + offH);
  float* stats = (float*)(ws + offS);
  float* y = (float*)d_out;

  k_stats<<<dim3(BB * DD), dim3(256), 0, stream>>>(BCdt, stats, hmat);
  k_prep<<<dim3(BB * 2 * 64), dim3(256), 0, stream>>>(BCdt, stats, AB, BCt);
  k_hmat<<<dim3(BB * 6 * 8), dim3(256), 0, stream>>>(x, AB, hmat);
  k_y<<<dim3(BB * 6 * 32), dim3(256), 0, stream>>>(hmat, BCt, y);
}